// Round 9
// baseline (80.220 us; speedup 1.0000x reference)
//
#include <hip/hip_runtime.h>

#define N_RAY 131072
#define NS 128
#define BIG_DELTA 1e10f
#define EPS 1e-10f
#define NWAVE 8192          // persistent waves (2048 blocks x 4 waves)
#define ITERS (N_RAY / NWAVE)   // 16 rays per wave

typedef float f32x2 __attribute__((ext_vector_type(2)));

// DPP move with explicit identity for invalid/masked lanes (bound_ctrl=false).
// Semantics HW-verified in R6/R7 (passed): row_shr:N, wave_shr:1, wave_shl:1,
// row_bcast:15/31 per LLVM atomic-optimizer scan pattern.
#define DPPF(OLD, V, CTRL, RM) \
  __int_as_float(__builtin_amdgcn_update_dpp(__float_as_int(OLD), __float_as_int(V), (CTRL), (RM), 0xf, false))

// Inclusive multiply-scan over 64 lanes (identity = 1.0). 6 DPP ops.
__device__ __forceinline__ float mul_scan_incl(float p) {
    p *= DPPF(1.0f, p, 0x111, 0xf);   // row_shr:1
    p *= DPPF(1.0f, p, 0x112, 0xf);   // row_shr:2
    p *= DPPF(1.0f, p, 0x114, 0xf);   // row_shr:4
    p *= DPPF(1.0f, p, 0x118, 0xf);   // row_shr:8
    p *= DPPF(1.0f, p, 0x142, 0xa);   // row_bcast:15 -> rows 1,3
    p *= DPPF(1.0f, p, 0x143, 0xc);   // row_bcast:31 -> rows 2,3
    return p;
}

// Wave sum; total lands in lane 63. 6 DPP ops.
__device__ __forceinline__ float wave_sum63(float v) {
    v += DPPF(0.0f, v, 0x111, 0xf);
    v += DPPF(0.0f, v, 0x112, 0xf);
    v += DPPF(0.0f, v, 0x114, 0xf);
    v += DPPF(0.0f, v, 0x118, 0xf);
    v += DPPF(0.0f, v, 0x142, 0xa);
    v += DPPF(0.0f, v, 0x143, 0xc);
    return v;
}

__device__ __forceinline__ float2 ld2(const float* p) {
    return *reinterpret_cast<const float2*>(p);
}

// Persistent waves: each wave owns rays {wid, wid+NWAVE, ...}, one ray per
// iteration, with next-ray loads issued BEFORE current-ray compute so HBM
// latency hides under the scan/reduce chain. Weights stored non-temporally
// (write-once stream) to avoid evicting L3-resident inputs.
__global__ __launch_bounds__(256) void volrender_kernel(
    const float* __restrict__ rgb,
    const float* __restrict__ sigma,
    const float* __restrict__ z_vals,
    const int* __restrict__ wb_flag,
    float* __restrict__ out)
{
    const int lane = threadIdx.x & 63;
    const int wid  = (blockIdx.x * blockDim.x + threadIdx.x) >> 6;  // 0..NWAVE-1
    const int wb   = *wb_flag;   // uniform scalar load, once
    float* wout = out + (size_t)N_RAY * 5;

    size_t ray = wid;

    // prologue: load first ray
    float2 z  = ld2(&z_vals[ray * NS + 2 * lane]);
    float2 sg = ld2(&sigma [ray * NS + 2 * lane]);
    const float* rp = rgb + ray * (NS * 3) + 6 * lane;
    float2 c01 = ld2(rp), c23 = ld2(rp + 2), c45 = ld2(rp + 4);

    #pragma unroll 2
    for (int it = 0; it < ITERS; ++it) {
        // ---- issue next ray's loads first (prefetch into regs)
        float2 zn, sn, n01, n23, n45;
        const size_t nray = ray + NWAVE;
        if (it < ITERS - 1) {
            zn = ld2(&z_vals[nray * NS + 2 * lane]);
            sn = ld2(&sigma [nray * NS + 2 * lane]);
            const float* np = rgb + nray * (NS * 3) + 6 * lane;
            n01 = ld2(np); n23 = ld2(np + 2); n45 = ld2(np + 4);
        }

        // ---- compute current ray
        // z[2l+2] from lane l+1 (wave_shl:1); lane 63 -> BIG_DELTA
        float znext = DPPF(0.0f, z.x, 0x130, 0xf);
        float d0 = z.y - z.x;
        float d1 = (lane == 63) ? BIG_DELTA : (znext - z.y);

        float e0 = __expf(-d0 * fmaxf(sg.x, 0.0f));
        float e1 = __expf(-d1 * fmaxf(sg.y, 0.0f));
        float a0 = 1.0f - e0, a1 = 1.0f - e1;
        float t0 = e0 + EPS,  t1 = e1 + EPS;

        float p = mul_scan_incl(t0 * t1);
        float E = DPPF(1.0f, p, 0x138, 0xf);   // exclusive; lane0 = 1.0

        float w0 = a0 * E;
        float w1 = a1 * (E * t0);

        // weights: non-temporal write-once stream (native vector type for the builtin)
        {
            f32x2 wv; wv.x = w0; wv.y = w1;
            __builtin_nontemporal_store(
                wv, reinterpret_cast<f32x2*>(&wout[ray * NS + 2 * lane]));
        }

        // partials: s0 rgb=(c01.x,c01.y,c23.x), s1 rgb=(c23.y,c45.x,c45.y)
        float r   = w0 * c01.x + w1 * c23.y;
        float g   = w0 * c01.y + w1 * c45.x;
        float b   = w0 * c23.x + w1 * c45.y;
        float dep = w0 * z.x   + w1 * z.y;

        r   = wave_sum63(r);
        g   = wave_sum63(g);
        b   = wave_sum63(b);
        dep = wave_sum63(dep);

        if (lane == 63) {
            // opacity = 1 - prod(t) (EPS-sum term <= 1.3e-8, << threshold)
            float op = 1.0f - p;
            const float add = wb ? (1.0f - op) : 0.0f;
            out[ray * 3 + 0] = r + add;
            out[ray * 3 + 1] = g + add;
            out[ray * 3 + 2] = b + add;
            out[(size_t)N_RAY * 3 + ray] = dep;
            out[(size_t)N_RAY * 4 + ray] = op;
        }

        if (it < ITERS - 1) {
            z = zn; sg = sn; c01 = n01; c23 = n23; c45 = n45;
        }
        ray = nray;
    }
}

extern "C" void kernel_launch(void* const* d_in, const int* in_sizes, int n_in,
                              void* d_out, int out_size, void* d_ws, size_t ws_size,
                              hipStream_t stream) {
    const float* rgb    = (const float*)d_in[0];
    const float* sigma  = (const float*)d_in[1];
    const float* z_vals = (const float*)d_in[2];
    const int*   wb     = (const int*)d_in[3];
    float* out = (float*)d_out;

    const int blocks = NWAVE / 4;   // 2048 blocks x 256 threads (4 waves)
    volrender_kernel<<<blocks, 256, 0, stream>>>(rgb, sigma, z_vals, wb, out);
}